// Round 6
// baseline (286.623 us; speedup 1.0000x reference)
//
#include <hip/hip_runtime.h>

// FindInstancePeaks: fused conv backbone + global peak finding.
// crops (128,192,192,1) f32 -> conv1 3x3 s2 SAME (1->32) + relu
//                          -> conv2 3x3 s1 SAME (32->17) = cms (128,96,96,17)
// -> per (b,n): argmax over 96x96, quarter-pixel sign refine, *2, NaN<0.2.
//
// R6: R5's conv2 mixed s_load (W2 global) with ds_read (hrow) in lgkm ->
// out-of-order SMEM forces lgkmcnt(0) drains, ~35% stall. Fix: weights back
// in LDS (per-g 2.9 KB slice), read as BROADCAST b128 (same addr all lanes
// = ~2 cyc on LDS pipe, m136) from 16B-aligned 20-float groups; hrow stays
// hoisted per-cl (R5). Hot loop lgkm = DS-only -> in-order fine-grained
// pipelining. LDS-pipe budget ~17 cyc per (k,cl) vs 34 VALU -> VALU-bound.
// Note: v_pk_fma_f32 is NOT a lever on CDNA4 (157.3 TF = unpacked rate).

#define NCH 17
#define C1 32
#define TS2 32          // cms tile (32x32)
#define HT2 34          // h rows/cols needed (tile+2)
#define HS 36           // s_h col stride (floats): 144 B rows, 16B-aligned
#define IN2 69          // input patch: 2*32+5
#define CG 4            // conv1 channels per group
#define NG 8            // groups
#define WPAD 20         // padded floats per (k,cl) weight group (80 B, 16B-aligned)

__device__ __forceinline__ unsigned long long pack_key(float v, unsigned flat) {
    unsigned ub = __float_as_uint(v);
    ub = (ub & 0x80000000u) ? ~ub : (ub | 0x80000000u);   // monotone float->uint
    return ((unsigned long long)ub << 32) | (unsigned)(~flat); // ~flat: ties -> lowest idx
}

__global__ __launch_bounds__(256, 3) void conv_peaks_kernel(
    const float* __restrict__ crops, const float* __restrict__ W1g,
    const float* __restrict__ b1g, const float* __restrict__ W2g,
    const float* __restrict__ b2g, unsigned long long* __restrict__ peaks) {
    __shared__ float s_in[IN2 * IN2];                        // 19044 B
    __shared__ __align__(16) float s_h[CG * HT2 * HS];       // 19584 B
    __shared__ __align__(16) float s_w2[9 * CG * WPAD];      // 2880 B

    const int t = threadIdx.x;
    const int b = blockIdx.y;
    const int ty0 = (blockIdx.x / 3) * TS2;
    const int tx0 = (blockIdx.x % 3) * TS2;
    const int iy0 = 2 * ty0 - 2;
    const int ix0 = 2 * tx0 - 2;
    const float* cb = crops + b * 192 * 192;

    // --- stage input patch (zero-padded at image borders) ---
    for (int p = t; p < IN2 * IN2; p += 256) {
        int r = p / IN2, cc = p - r * IN2;
        int iy = iy0 + r, ix = ix0 + cc;
        float v = 0.f;
        if (iy >= 0 && ix >= 0 && iy < 192 && ix < 192) v = cb[iy * 192 + ix];
        s_in[p] = v;
    }

    // thread -> 4 contiguous pixels: row ly, cols lx0..lx0+3
    const int ly = t >> 3;            // 0..31
    const int lx0 = (t & 7) * 4;      // 0,4,...,28
    float acc[NCH][4];
#pragma unroll
    for (int n = 0; n < NCH; ++n)
#pragma unroll
        for (int p = 0; p < 4; ++p) acc[n][p] = 0.f;

#pragma unroll 1
    for (int g = 0; g < NG; ++g) {
        __syncthreads();   // prev conv2 reads / staging done before overwrite

        // stage W2 slice for this channel group: (k,cl,n) -> group*20+n
        for (int p = t; p < 9 * CG * NCH; p += 256) {
            int k = p / (CG * NCH);
            int rem = p - k * (CG * NCH);
            int cl = rem / NCH, n = rem - cl * NCH;
            s_w2[(k * CG + cl) * WPAD + n] =
                W2g[(k * C1 + g * CG + cl) * NCH + n];
        }

        // conv1 + relu for this group's 4 channels
        for (int p = t; p < HT2 * HT2; p += 256) {
            int r = p / HT2, cc = p - r * HT2;
            int hy = ty0 - 1 + r, hx = tx0 - 1 + cc;
            bool valid = (hy >= 0) && (hy < 96) && (hx >= 0) && (hx < 96);
            float in9[9];
#pragma unroll
            for (int q = 0; q < 9; ++q)
                in9[q] = s_in[(2 * r + q / 3) * IN2 + (2 * cc + q % 3)];
#pragma unroll
            for (int cl = 0; cl < CG; ++cl) {
                int c = g * CG + cl;
                float a = b1g[c];
#pragma unroll
                for (int q = 0; q < 9; ++q) a = fmaf(in9[q], W1g[q * C1 + c], a);
                a = valid ? fmaxf(a, 0.f) : 0.f;
                s_h[cl * (HT2 * HS) + r * HS + cc] = a;
            }
        }
        __syncthreads();

        // conv2 partial: per cl, 6 hrow loads + per k 5 broadcast weight
        // loads; everything else is register FMAs. DS-only lgkm traffic.
#pragma unroll 1
        for (int cl = 0; cl < CG; ++cl) {
            float hrow[3][6];
            const float* hp = s_h + cl * (HT2 * HS) + ly * HS + lx0;
#pragma unroll
            for (int r = 0; r < 3; ++r) {
                float4 h4 = *(const float4*)(hp + r * HS);       // ds_read_b128
                float2 h2 = *(const float2*)(hp + r * HS + 4);   // ds_read_b64
                hrow[r][0] = h4.x; hrow[r][1] = h4.y;
                hrow[r][2] = h4.z; hrow[r][3] = h4.w;
                hrow[r][4] = h2.x; hrow[r][5] = h2.y;
            }
#pragma unroll
            for (int k = 0; k < 9; ++k) {
                const int ky = k / 3, kx = k - ky * 3;
                const float* wb = s_w2 + (k * CG + cl) * WPAD;   // broadcast
                float4 wa = *(const float4*)(wb);                // ds_read_b128
                float4 wbv = *(const float4*)(wb + 4);
                float4 wc = *(const float4*)(wb + 8);
                float4 wd = *(const float4*)(wb + 12);
                float we = wb[16];
                float w[NCH] = {wa.x, wa.y, wa.z, wa.w,
                                wbv.x, wbv.y, wbv.z, wbv.w,
                                wc.x, wc.y, wc.z, wc.w,
                                wd.x, wd.y, wd.z, wd.w, we};
#pragma unroll
                for (int n = 0; n < NCH; ++n)
#pragma unroll
                    for (int p = 0; p < 4; ++p)
                        acc[n][p] = fmaf(hrow[ky][kx + p], w[n], acc[n][p]);
            }
        }
    }

    // --- per-channel argmax: in-thread max over 4 px, then wave reduce ---
    const int yg = ty0 + ly, xg = tx0 + lx0;
    const int lane = t & 63;
#pragma unroll
    for (int n = 0; n < NCH; ++n) {
        float bb = b2g[n];
        unsigned long long pk = pack_key(acc[n][0] + bb, (unsigned)(yg * 96 + xg));
#pragma unroll
        for (int p = 1; p < 4; ++p) {
            unsigned long long o = pack_key(acc[n][p] + bb, (unsigned)(yg * 96 + xg + p));
            if (o > pk) pk = o;
        }
#pragma unroll
        for (int off = 32; off; off >>= 1) {
            unsigned long long o = __shfl_down(pk, off, 64);
            if (o > pk) pk = o;
        }
        if (lane == 0) atomicMax(&peaks[b * NCH + n], pk);
    }
}

// One 64-lane wave per (b,n): decode peak, recompute 4 clipped neighbor cms
// values from crops (b2 bias cancels in differences), emit (x,y,val).
__global__ __launch_bounds__(64) void refine_kernel(
    const float* __restrict__ crops, const float* __restrict__ W1g,
    const float* __restrict__ b1g, const float* __restrict__ W2g,
    const unsigned long long* __restrict__ peaks, float* __restrict__ out) {
    const int bn = blockIdx.x;          // 0..128*17-1
    const int b = bn / NCH, n = bn % NCH;
    const int lane = threadIdx.x;

    unsigned long long pk = peaks[bn];
    unsigned key = (unsigned)(pk >> 32);
    unsigned fbits = (key & 0x80000000u) ? (key ^ 0x80000000u) : ~key;
    float val = __uint_as_float(fbits);
    int flat = (int)(~(unsigned)(pk & 0xffffffffu));
    int yi = flat / 96, xi = flat - yi * 96;

    // neighbor j: 0:(yi,xi+1) 1:(yi,xi-1) 2:(yi+1,xi) 3:(yi-1,xi), clipped
    const int j = lane >> 4;
    int yy = yi + ((j == 2) ? 1 : 0) - ((j == 3) ? 1 : 0);
    int xx = xi + ((j == 0) ? 1 : 0) - ((j == 1) ? 1 : 0);
    yy = min(max(yy, 0), 95);
    xx = min(max(xx, 0), 95);

    const float* cb = crops + b * 192 * 192;
    float part = 0.f;
#pragma unroll
    for (int ci = 0; ci < 2; ++ci) {
        const int c = (lane & 15) + ci * 16;
#pragma unroll 1
        for (int ky = 0; ky < 3; ++ky) {
#pragma unroll 1
            for (int kx = 0; kx < 3; ++kx) {
                int hy = yy + ky - 1, hx = xx + kx - 1;
                float hval = 0.f;
                if (hy >= 0 && hy < 96 && hx >= 0 && hx < 96) {
                    float a = b1g[c];
#pragma unroll
                    for (int q = 0; q < 9; ++q) {
                        int iy = 2 * hy + q / 3, ix = 2 * hx + q % 3;
                        float iv = (iy < 192 && ix < 192) ? cb[iy * 192 + ix] : 0.f;
                        a = fmaf(iv, W1g[(q / 3 * 3 + q % 3) * C1 + c], a);
                    }
                    hval = fmaxf(a, 0.f);
                }
                part = fmaf(hval, W2g[((ky * 3 + kx) * C1 + c) * NCH + n], part);
            }
        }
    }
    // sum the 16 lanes of each neighbor group
    for (int off = 8; off; off >>= 1) part += __shfl_down(part, off, 16);
    float g0 = __shfl(part, 0, 64);
    float g1 = __shfl(part, 16, 64);
    float g2 = __shfl(part, 32, 64);
    float g3 = __shfl(part, 48, 64);

    if (lane == 0) {
        float d0 = g0 - g1, d1 = g2 - g3;
        float sx = (d0 > 0.f) ? 1.f : ((d0 < 0.f) ? -1.f : 0.f);
        float sy = (d1 > 0.f) ? 1.f : ((d1 < 0.f) ? -1.f : 0.f);
        float px = ((float)xi + 0.25f * sx) * 2.f;
        float py = ((float)yi + 0.25f * sy) * 2.f;
        if (!(val >= 0.2f)) {
            px = __int_as_float(0x7fc00000);
            py = __int_as_float(0x7fc00000);
        }
        out[bn * 3 + 0] = px;
        out[bn * 3 + 1] = py;
        out[bn * 3 + 2] = val;
    }
}

extern "C" void kernel_launch(void* const* d_in, const int* in_sizes, int n_in,
                              void* d_out, int out_size, void* d_ws, size_t ws_size,
                              hipStream_t stream) {
    const float* crops = (const float*)d_in[0];
    const float* W1 = (const float*)d_in[1];
    const float* b1 = (const float*)d_in[2];
    const float* W2 = (const float*)d_in[3];
    const float* b2 = (const float*)d_in[4];
    float* out = (float*)d_out;
    unsigned long long* peaks = (unsigned long long*)d_ws;

    hipMemsetAsync(d_ws, 0, 128 * NCH * sizeof(unsigned long long), stream);

    dim3 gridB(9, 128);   // 3x3 tiles of 32x32 over 96x96, per image
    conv_peaks_kernel<<<gridB, 256, 0, stream>>>(crops, W1, b1, W2, b2, peaks);
    refine_kernel<<<128 * NCH, 64, 0, stream>>>(crops, W1, b1, W2, peaks, out);
}

// Round 7
// 269.272 us; speedup vs baseline: 1.0644x; 1.0644x over previous
//
#include <hip/hip_runtime.h>

// FindInstancePeaks: fused conv backbone + global peak finding.
// crops (128,192,192,1) f32 -> conv1 3x3 s2 SAME (1->32) + relu
//                          -> conv2 3x3 s1 SAME (32->17) = cms (128,96,96,17)
// -> per (b,n): argmax over 96x96, quarter-pixel sign refine, *2, NaN<0.2.
//
// R7: R6's regression was a scratch spill (VGPR 84, WRITE +16 MB) caused by
// the float w[17] intermediate array. Merge the two proven-good halves:
//  - R5's hoisted per-cl hrow[3][6] (6 ds_reads serve 612 FMAs);
//  - R3's broadcast-LDS weights consumed DIRECTLY as float4 components in
//    fully-unrolled STEP macros (R3 ran this spill-free at a 128-reg budget).
// W2 slice stored SoA (4x float4-array + scalar array) so each (k,cl) is
// 4 broadcast ds_read_b128 + 1 b32. Hot loop lgkm = DS-only (no s_load
// mixing -> no lgkmcnt(0) drains).

#define NCH 17
#define C1 32
#define TS2 32          // cms tile (32x32)
#define HT2 34          // h rows/cols needed (tile+2)
#define HS 36           // s_h col stride (floats): 144 B rows, 16B-aligned
#define IN2 69          // input patch: 2*32+5
#define CG 4            // conv1 channels per group
#define NG 8            // groups

__device__ __forceinline__ unsigned long long pack_key(float v, unsigned flat) {
    unsigned ub = __float_as_uint(v);
    ub = (ub & 0x80000000u) ? ~ub : (ub | 0x80000000u);   // monotone float->uint
    return ((unsigned long long)ub << 32) | (unsigned)(~flat); // ~flat: ties -> lowest idx
}

__global__ __launch_bounds__(256, 3) void conv_peaks_kernel(
    const float* __restrict__ crops, const float* __restrict__ W1g,
    const float* __restrict__ b1g, const float* __restrict__ W2g,
    const float* __restrict__ b2g, unsigned long long* __restrict__ peaks) {
    __shared__ float s_in[IN2 * IN2];                        // 19044 B
    __shared__ __align__(16) float s_h[CG * HT2 * HS];       // 19584 B
    __shared__ __align__(16) float s_w2a[9 * CG * 4];        // 576 B  (n 0..3)
    __shared__ __align__(16) float s_w2b[9 * CG * 4];        // 576 B  (n 4..7)
    __shared__ __align__(16) float s_w2c[9 * CG * 4];        // 576 B  (n 8..11)
    __shared__ __align__(16) float s_w2d[9 * CG * 4];        // 576 B  (n 12..15)
    __shared__ float s_w2e[9 * CG];                          // 144 B  (n 16)

    const int t = threadIdx.x;
    const int b = blockIdx.y;
    const int ty0 = (blockIdx.x / 3) * TS2;
    const int tx0 = (blockIdx.x % 3) * TS2;
    const int iy0 = 2 * ty0 - 2;
    const int ix0 = 2 * tx0 - 2;
    const float* cb = crops + b * 192 * 192;

    // --- stage input patch (zero-padded at image borders) ---
    for (int p = t; p < IN2 * IN2; p += 256) {
        int r = p / IN2, cc = p - r * IN2;
        int iy = iy0 + r, ix = ix0 + cc;
        float v = 0.f;
        if (iy >= 0 && ix >= 0 && iy < 192 && ix < 192) v = cb[iy * 192 + ix];
        s_in[p] = v;
    }

    // thread -> 4 contiguous pixels: row ly, cols lx0..lx0+3
    const int ly = t >> 3;            // 0..31
    const int lx0 = (t & 7) * 4;      // 0,4,...,28
    float acc[NCH][4];
#pragma unroll
    for (int n = 0; n < NCH; ++n)
#pragma unroll
        for (int p = 0; p < 4; ++p) acc[n][p] = 0.f;

#pragma unroll 1
    for (int g = 0; g < NG; ++g) {
        __syncthreads();   // prev conv2 reads / staging done before overwrite

        // stage W2 slice for this channel group (SoA float4 groups)
        for (int p = t; p < 9 * CG * NCH; p += 256) {
            int k = p / (CG * NCH);
            int rem = p - k * (CG * NCH);
            int cl = rem / NCH, n = rem - cl * NCH;
            float w = W2g[(k * C1 + g * CG + cl) * NCH + n];
            int kcl = k * CG + cl;
            if (n < 4)       s_w2a[kcl * 4 + n] = w;
            else if (n < 8)  s_w2b[kcl * 4 + n - 4] = w;
            else if (n < 12) s_w2c[kcl * 4 + n - 8] = w;
            else if (n < 16) s_w2d[kcl * 4 + n - 12] = w;
            else             s_w2e[kcl] = w;
        }

        // conv1 + relu for this group's 4 channels
        for (int p = t; p < HT2 * HT2; p += 256) {
            int r = p / HT2, cc = p - r * HT2;
            int hy = ty0 - 1 + r, hx = tx0 - 1 + cc;
            bool valid = (hy >= 0) && (hy < 96) && (hx >= 0) && (hx < 96);
            float in9[9];
#pragma unroll
            for (int q = 0; q < 9; ++q)
                in9[q] = s_in[(2 * r + q / 3) * IN2 + (2 * cc + q % 3)];
#pragma unroll
            for (int cl = 0; cl < CG; ++cl) {
                int c = g * CG + cl;
                float a = b1g[c];
#pragma unroll
                for (int q = 0; q < 9; ++q) a = fmaf(in9[q], W1g[q * C1 + c], a);
                a = valid ? fmaxf(a, 0.f) : 0.f;
                s_h[cl * (HT2 * HS) + r * HS + cc] = a;
            }
        }
        __syncthreads();

        // conv2 partial: per cl, 6 hrow loads; per k, 5 broadcast weight
        // loads consumed directly as components. DS-only lgkm traffic.
#pragma unroll 1
        for (int cl = 0; cl < CG; ++cl) {
            float hrow[3][6];
            const float* hp = s_h + cl * (HT2 * HS) + ly * HS + lx0;
#pragma unroll
            for (int r = 0; r < 3; ++r) {
                float4 h4 = *(const float4*)(hp + r * HS);       // ds_read_b128
                float2 h2 = *(const float2*)(hp + r * HS + 4);   // ds_read_b64
                hrow[r][0] = h4.x; hrow[r][1] = h4.y;
                hrow[r][2] = h4.z; hrow[r][3] = h4.w;
                hrow[r][4] = h2.x; hrow[r][5] = h2.y;
            }
#pragma unroll
            for (int k = 0; k < 9; ++k) {
                const int ky = k / 3, kx = k - ky * 3;
                const int kcl = k * CG + cl;
                float4 wa = *(const float4*)(s_w2a + kcl * 4);   // broadcast b128
                float4 wb = *(const float4*)(s_w2b + kcl * 4);
                float4 wc = *(const float4*)(s_w2c + kcl * 4);
                float4 wd = *(const float4*)(s_w2d + kcl * 4);
                float we = s_w2e[kcl];
#define STEP(NI, WV) { float wv = (WV); \
                acc[NI][0] = fmaf(hrow[ky][kx + 0], wv, acc[NI][0]); \
                acc[NI][1] = fmaf(hrow[ky][kx + 1], wv, acc[NI][1]); \
                acc[NI][2] = fmaf(hrow[ky][kx + 2], wv, acc[NI][2]); \
                acc[NI][3] = fmaf(hrow[ky][kx + 3], wv, acc[NI][3]); }
                STEP(0, wa.x)  STEP(1, wa.y)  STEP(2, wa.z)  STEP(3, wa.w)
                STEP(4, wb.x)  STEP(5, wb.y)  STEP(6, wb.z)  STEP(7, wb.w)
                STEP(8, wc.x)  STEP(9, wc.y)  STEP(10, wc.z) STEP(11, wc.w)
                STEP(12, wd.x) STEP(13, wd.y) STEP(14, wd.z) STEP(15, wd.w)
                STEP(16, we)
#undef STEP
            }
        }
    }

    // --- per-channel argmax: in-thread max over 4 px, then wave reduce ---
    const int yg = ty0 + ly, xg = tx0 + lx0;
    const int lane = t & 63;
#pragma unroll
    for (int n = 0; n < NCH; ++n) {
        float bb = b2g[n];
        unsigned long long pk = pack_key(acc[n][0] + bb, (unsigned)(yg * 96 + xg));
#pragma unroll
        for (int p = 1; p < 4; ++p) {
            unsigned long long o = pack_key(acc[n][p] + bb, (unsigned)(yg * 96 + xg + p));
            if (o > pk) pk = o;
        }
#pragma unroll
        for (int off = 32; off; off >>= 1) {
            unsigned long long o = __shfl_down(pk, off, 64);
            if (o > pk) pk = o;
        }
        if (lane == 0) atomicMax(&peaks[b * NCH + n], pk);
    }
}

// One 64-lane wave per (b,n): decode peak, recompute 4 clipped neighbor cms
// values from crops (b2 bias cancels in differences), emit (x,y,val).
__global__ __launch_bounds__(64) void refine_kernel(
    const float* __restrict__ crops, const float* __restrict__ W1g,
    const float* __restrict__ b1g, const float* __restrict__ W2g,
    const unsigned long long* __restrict__ peaks, float* __restrict__ out) {
    const int bn = blockIdx.x;          // 0..128*17-1
    const int b = bn / NCH, n = bn % NCH;
    const int lane = threadIdx.x;

    unsigned long long pk = peaks[bn];
    unsigned key = (unsigned)(pk >> 32);
    unsigned fbits = (key & 0x80000000u) ? (key ^ 0x80000000u) : ~key;
    float val = __uint_as_float(fbits);
    int flat = (int)(~(unsigned)(pk & 0xffffffffu));
    int yi = flat / 96, xi = flat - yi * 96;

    // neighbor j: 0:(yi,xi+1) 1:(yi,xi-1) 2:(yi+1,xi) 3:(yi-1,xi), clipped
    const int j = lane >> 4;
    int yy = yi + ((j == 2) ? 1 : 0) - ((j == 3) ? 1 : 0);
    int xx = xi + ((j == 0) ? 1 : 0) - ((j == 1) ? 1 : 0);
    yy = min(max(yy, 0), 95);
    xx = min(max(xx, 0), 95);

    const float* cb = crops + b * 192 * 192;
    float part = 0.f;
#pragma unroll
    for (int ci = 0; ci < 2; ++ci) {
        const int c = (lane & 15) + ci * 16;
#pragma unroll 1
        for (int ky = 0; ky < 3; ++ky) {
#pragma unroll 1
            for (int kx = 0; kx < 3; ++kx) {
                int hy = yy + ky - 1, hx = xx + kx - 1;
                float hval = 0.f;
                if (hy >= 0 && hy < 96 && hx >= 0 && hx < 96) {
                    float a = b1g[c];
#pragma unroll
                    for (int q = 0; q < 9; ++q) {
                        int iy = 2 * hy + q / 3, ix = 2 * hx + q % 3;
                        float iv = (iy < 192 && ix < 192) ? cb[iy * 192 + ix] : 0.f;
                        a = fmaf(iv, W1g[(q / 3 * 3 + q % 3) * C1 + c], a);
                    }
                    hval = fmaxf(a, 0.f);
                }
                part = fmaf(hval, W2g[((ky * 3 + kx) * C1 + c) * NCH + n], part);
            }
        }
    }
    // sum the 16 lanes of each neighbor group
    for (int off = 8; off; off >>= 1) part += __shfl_down(part, off, 16);
    float g0 = __shfl(part, 0, 64);
    float g1 = __shfl(part, 16, 64);
    float g2 = __shfl(part, 32, 64);
    float g3 = __shfl(part, 48, 64);

    if (lane == 0) {
        float d0 = g0 - g1, d1 = g2 - g3;
        float sx = (d0 > 0.f) ? 1.f : ((d0 < 0.f) ? -1.f : 0.f);
        float sy = (d1 > 0.f) ? 1.f : ((d1 < 0.f) ? -1.f : 0.f);
        float px = ((float)xi + 0.25f * sx) * 2.f;
        float py = ((float)yi + 0.25f * sy) * 2.f;
        if (!(val >= 0.2f)) {
            px = __int_as_float(0x7fc00000);
            py = __int_as_float(0x7fc00000);
        }
        out[bn * 3 + 0] = px;
        out[bn * 3 + 1] = py;
        out[bn * 3 + 2] = val;
    }
}

extern "C" void kernel_launch(void* const* d_in, const int* in_sizes, int n_in,
                              void* d_out, int out_size, void* d_ws, size_t ws_size,
                              hipStream_t stream) {
    const float* crops = (const float*)d_in[0];
    const float* W1 = (const float*)d_in[1];
    const float* b1 = (const float*)d_in[2];
    const float* W2 = (const float*)d_in[3];
    const float* b2 = (const float*)d_in[4];
    float* out = (float*)d_out;
    unsigned long long* peaks = (unsigned long long*)d_ws;

    hipMemsetAsync(d_ws, 0, 128 * NCH * sizeof(unsigned long long), stream);

    dim3 gridB(9, 128);   // 3x3 tiles of 32x32 over 96x96, per image
    conv_peaks_kernel<<<gridB, 256, 0, stream>>>(crops, W1, b1, W2, b2, peaks);
    refine_kernel<<<128 * NCH, 64, 0, stream>>>(crops, W1, b1, W2, peaks, out);
}

// Round 8
// 223.168 us; speedup vs baseline: 1.2843x; 1.2066x over previous
//
#include <hip/hip_runtime.h>

// FindInstancePeaks: fused conv backbone + global peak finding.
// crops (128,192,192,1) f32 -> conv1 3x3 s2 SAME (1->32) + relu
//                          -> conv2 3x3 s1 SAME (32->17) = cms (128,96,96,17)
// -> per (b,n): argmax over 96x96, quarter-pixel sign refine, *2, NaN<0.2.
//
// R8: revert conv2 to R5's proven spill-free body (weights via s_load ->
// SGPRs; every LDS-weight variant R3/R6/R7 spilled the unified reg file).
// Changes vs R5:
//  (1) __launch_bounds__(256,4): unified usage ~124 fits the 128 budget
//      (R3 proved this footprint at (256,4)); LDS 38912 -> 4 blocks/CU,
//      dispatch 1152/1024 = 1.125 rounds instead of 1.5 (tail fix).
//  (2) refine kernel: hoist the channel-independent 7x7 crops patch
//      (49 broadcast loads) out of the channel loop; inner 162 FMAs are
//      load-free. Was 162 dependent global loads per lane.

#define NCH 17
#define C1 32
#define TS2 32          // cms tile (32x32)
#define HT2 34          // h rows/cols needed (tile+2)
#define HS 36           // s_h col stride (floats): 144 B rows, 16B-aligned
#define IN2 69          // input patch: 2*32+5
#define CG 4            // conv1 channels per group
#define NG 8            // groups

__device__ __forceinline__ unsigned long long pack_key(float v, unsigned flat) {
    unsigned ub = __float_as_uint(v);
    ub = (ub & 0x80000000u) ? ~ub : (ub | 0x80000000u);   // monotone float->uint
    return ((unsigned long long)ub << 32) | (unsigned)(~flat); // ~flat: ties -> lowest idx
}

__global__ __launch_bounds__(256, 4) void conv_peaks_kernel(
    const float* __restrict__ crops, const float* __restrict__ W1g,
    const float* __restrict__ b1g, const float* __restrict__ W2g,
    const float* __restrict__ b2g, unsigned long long* __restrict__ peaks) {
    __shared__ float s_in[IN2 * IN2];                        // 19044 B
    __shared__ __align__(16) float s_h[CG * HT2 * HS];       // 19584 B

    const int t = threadIdx.x;
    const int b = blockIdx.y;
    const int ty0 = (blockIdx.x / 3) * TS2;
    const int tx0 = (blockIdx.x % 3) * TS2;
    const int iy0 = 2 * ty0 - 2;
    const int ix0 = 2 * tx0 - 2;
    const float* cb = crops + b * 192 * 192;

    // --- stage input patch (zero-padded at image borders) ---
    for (int p = t; p < IN2 * IN2; p += 256) {
        int r = p / IN2, cc = p - r * IN2;
        int iy = iy0 + r, ix = ix0 + cc;
        float v = 0.f;
        if (iy >= 0 && ix >= 0 && iy < 192 && ix < 192) v = cb[iy * 192 + ix];
        s_in[p] = v;
    }

    // thread -> 4 contiguous pixels: row ly, cols lx0..lx0+3
    const int ly = t >> 3;            // 0..31
    const int lx0 = (t & 7) * 4;      // 0,4,...,28
    float acc[NCH][4];
#pragma unroll
    for (int n = 0; n < NCH; ++n)
#pragma unroll
        for (int p = 0; p < 4; ++p) acc[n][p] = 0.f;

#pragma unroll 1
    for (int g = 0; g < NG; ++g) {
        __syncthreads();   // prev conv2 reads / staging done before overwrite

        // conv1 + relu for this group's 4 channels
        for (int p = t; p < HT2 * HT2; p += 256) {
            int r = p / HT2, cc = p - r * HT2;
            int hy = ty0 - 1 + r, hx = tx0 - 1 + cc;
            bool valid = (hy >= 0) && (hy < 96) && (hx >= 0) && (hx < 96);
            float in9[9];
#pragma unroll
            for (int q = 0; q < 9; ++q)
                in9[q] = s_in[(2 * r + q / 3) * IN2 + (2 * cc + q % 3)];
#pragma unroll
            for (int cl = 0; cl < CG; ++cl) {
                int c = g * CG + cl;
                float a = b1g[c];
#pragma unroll
                for (int q = 0; q < 9; ++q) a = fmaf(in9[q], W1g[q * C1 + c], a);
                a = valid ? fmaxf(a, 0.f) : 0.f;
                s_h[cl * (HT2 * HS) + r * HS + cc] = a;
            }
        }
        __syncthreads();

        // conv2 partial: per cl, load 3 h-rows x 6 floats once (LDS), read
        // W2 via uniform s_load (SGPRs - keeps VGPR pressure low), then
        // 612 register-only FMAs.
#pragma unroll 1
        for (int cl = 0; cl < CG; ++cl) {
            float hrow[3][6];
            const float* hp = s_h + cl * (HT2 * HS) + ly * HS + lx0;
#pragma unroll
            for (int r = 0; r < 3; ++r) {
                float4 h4 = *(const float4*)(hp + r * HS);       // ds_read_b128
                float2 h2 = *(const float2*)(hp + r * HS + 4);   // ds_read_b64
                hrow[r][0] = h4.x; hrow[r][1] = h4.y;
                hrow[r][2] = h4.z; hrow[r][3] = h4.w;
                hrow[r][4] = h2.x; hrow[r][5] = h2.y;
            }
            const int c = g * CG + cl;
#pragma unroll
            for (int k = 0; k < 9; ++k) {
                const int ky = k / 3, kx = k - ky * 3;
                const float* wb = W2g + (k * C1 + c) * NCH;  // uniform -> s_load
                float w[NCH];
#pragma unroll
                for (int n = 0; n < NCH; ++n) w[n] = wb[n];
#pragma unroll
                for (int n = 0; n < NCH; ++n)
#pragma unroll
                    for (int p = 0; p < 4; ++p)
                        acc[n][p] = fmaf(hrow[ky][kx + p], w[n], acc[n][p]);
            }
        }
    }

    // --- per-channel argmax: in-thread max over 4 px, then wave reduce ---
    const int yg = ty0 + ly, xg = tx0 + lx0;
    const int lane = t & 63;
#pragma unroll
    for (int n = 0; n < NCH; ++n) {
        float bb = b2g[n];
        unsigned long long pk = pack_key(acc[n][0] + bb, (unsigned)(yg * 96 + xg));
#pragma unroll
        for (int p = 1; p < 4; ++p) {
            unsigned long long o = pack_key(acc[n][p] + bb, (unsigned)(yg * 96 + xg + p));
            if (o > pk) pk = o;
        }
#pragma unroll
        for (int off = 32; off; off >>= 1) {
            unsigned long long o = __shfl_down(pk, off, 64);
            if (o > pk) pk = o;
        }
        if (lane == 0) atomicMax(&peaks[b * NCH + n], pk);
    }
}

// One 64-lane wave per (b,n): decode peak, recompute 4 clipped neighbor cms
// values (b2 cancels in the sign differences), emit (x,y,val).
// 16 lanes per neighbor, 2 channels per lane. The 7x7 crops patch for the
// neighbor is channel-independent: hoisted, 49 broadcast loads, then the
// whole channel loop is load-free FMAs (W1/W2 loads are per-lane c,
// coalesced across the 16-lane group).
__global__ __launch_bounds__(64) void refine_kernel(
    const float* __restrict__ crops, const float* __restrict__ W1g,
    const float* __restrict__ b1g, const float* __restrict__ W2g,
    const unsigned long long* __restrict__ peaks, float* __restrict__ out) {
    const int bn = blockIdx.x;          // 0..128*17-1
    const int b = bn / NCH, n = bn % NCH;
    const int lane = threadIdx.x;

    unsigned long long pk = peaks[bn];
    unsigned key = (unsigned)(pk >> 32);
    unsigned fbits = (key & 0x80000000u) ? (key ^ 0x80000000u) : ~key;
    float val = __uint_as_float(fbits);
    int flat = (int)(~(unsigned)(pk & 0xffffffffu));
    int yi = flat / 96, xi = flat - yi * 96;

    // neighbor j: 0:(yi,xi+1) 1:(yi,xi-1) 2:(yi+1,xi) 3:(yi-1,xi), clipped
    const int j = lane >> 4;
    int yy = yi + ((j == 2) ? 1 : 0) - ((j == 3) ? 1 : 0);
    int xx = xi + ((j == 0) ? 1 : 0) - ((j == 1) ? 1 : 0);
    yy = min(max(yy, 0), 95);
    xx = min(max(xx, 0), 95);

    // hoist 7x7 crops patch: rows 2yy-2..2yy+4, cols 2xx-2..2xx+4
    const float* cb = crops + b * 192 * 192;
    float pat[7][7];
#pragma unroll
    for (int r = 0; r < 7; ++r) {
        int iy = 2 * yy - 2 + r;
#pragma unroll
        for (int s = 0; s < 7; ++s) {
            int ix = 2 * xx - 2 + s;
            pat[r][s] = (iy >= 0 && iy < 192 && ix >= 0 && ix < 192)
                            ? cb[iy * 192 + ix] : 0.f;
        }
    }

    float part = 0.f;
#pragma unroll
    for (int ci = 0; ci < 2; ++ci) {
        const int c = (lane & 15) + ci * 16;
        const float bias = b1g[c];
        float w1[9];
#pragma unroll
        for (int q = 0; q < 9; ++q) w1[q] = W1g[q * C1 + c];
#pragma unroll
        for (int dy = 0; dy < 3; ++dy) {
#pragma unroll
            for (int dx = 0; dx < 3; ++dx) {
                int hy = yy - 1 + dy, hx = xx - 1 + dx;
                if (hy >= 0 && hy < 96 && hx >= 0 && hx < 96) {
                    float a = bias;
#pragma unroll
                    for (int qy = 0; qy < 3; ++qy)
#pragma unroll
                        for (int qx = 0; qx < 3; ++qx)
                            a = fmaf(pat[2 * dy + qy][2 * dx + qx],
                                     w1[qy * 3 + qx], a);
                    float hval = fmaxf(a, 0.f);
                    part = fmaf(hval, W2g[((dy * 3 + dx) * C1 + c) * NCH + n], part);
                }
            }
        }
    }
    // sum the 16 lanes of each neighbor group
    for (int off = 8; off; off >>= 1) part += __shfl_down(part, off, 16);
    float g0 = __shfl(part, 0, 64);
    float g1 = __shfl(part, 16, 64);
    float g2 = __shfl(part, 32, 64);
    float g3 = __shfl(part, 48, 64);

    if (lane == 0) {
        float d0 = g0 - g1, d1 = g2 - g3;
        float sx = (d0 > 0.f) ? 1.f : ((d0 < 0.f) ? -1.f : 0.f);
        float sy = (d1 > 0.f) ? 1.f : ((d1 < 0.f) ? -1.f : 0.f);
        float px = ((float)xi + 0.25f * sx) * 2.f;
        float py = ((float)yi + 0.25f * sy) * 2.f;
        if (!(val >= 0.2f)) {
            px = __int_as_float(0x7fc00000);
            py = __int_as_float(0x7fc00000);
        }
        out[bn * 3 + 0] = px;
        out[bn * 3 + 1] = py;
        out[bn * 3 + 2] = val;
    }
}

extern "C" void kernel_launch(void* const* d_in, const int* in_sizes, int n_in,
                              void* d_out, int out_size, void* d_ws, size_t ws_size,
                              hipStream_t stream) {
    const float* crops = (const float*)d_in[0];
    const float* W1 = (const float*)d_in[1];
    const float* b1 = (const float*)d_in[2];
    const float* W2 = (const float*)d_in[3];
    const float* b2 = (const float*)d_in[4];
    float* out = (float*)d_out;
    unsigned long long* peaks = (unsigned long long*)d_ws;

    hipMemsetAsync(d_ws, 0, 128 * NCH * sizeof(unsigned long long), stream);

    dim3 gridB(9, 128);   // 3x3 tiles of 32x32 over 96x96, per image
    conv_peaks_kernel<<<gridB, 256, 0, stream>>>(crops, W1, b1, W2, b2, peaks);
    refine_kernel<<<128 * NCH, 64, 0, stream>>>(crops, W1, b1, W2, peaks, out);
}